// Round 2
// baseline (227.332 us; speedup 1.0000x reference)
//
#include <hip/hip_runtime.h>

// CrossModalAttentionScorer — round 10: K3 gets the counted-vmcnt phase
// schedule (T3+T4+T5); prep row-paths go wave-per-row.
// B=16, R=1024, T=512, D=H=1024.
//
//   K1 prep_all: M2 = NT(Wr,Wq); Ws16; wqbr(+16); region16 + rdvec(=r.Ws0);
//                query16 + h1(=q.Ws1). Row paths: 4 rows/block, wave-per-row,
//                no LDS / no barriers (was 1 row/block + syncthreads).
//   K2 qp:       Qp = NT(query16, M2) — unchanged this round.
//   K3 fused:    accS = NT(region,Qp)+cvec, accH = NT(region, Ws2 (.) query),
//                h1 in epilogue. NEW schedule: 4 LDS half-slots (K=32 each,
//                96 KB), 3-half global_load_lds prefetch, per half:
//                  STAGE(h+3) ; vmcnt(9) ; barrier ; ds_read ; setprio(1)
//                  16 MFMA ; setprio(0) ; barrier
//                vmcnt never drains to 0 in the main loop (tail peels 9/6/3/0).
//                Addressing identical to r9 — only the sync schedule changed.
//   K4 combine:  out = HS/L + rdvec + bs over 16 col-chunks.
//
// r9 counters (K3): MfmaUtil 29 / VALUBusy 27 / HBM 9.7% / conflicts 0 ->
// the m97 barrier-drain ceiling; this is the documented fix (m218: +38-73%).

#define BD 16
#define RD 1024
#define TD 512
#define DD 1024
#define BR (BD * RD)

typedef _Float16 half8 __attribute__((ext_vector_type(8)));
typedef _Float16 half4 __attribute__((ext_vector_type(4)));
typedef float floatx4 __attribute__((ext_vector_type(4)));

__device__ __forceinline__ float wave_sum(float v) {
#pragma unroll
  for (int off = 32; off > 0; off >>= 1) v += __shfl_down(v, off);
  return v;
}

__device__ __forceinline__ half8 cvt8(float4 a, float4 b) {
  half8 h = {(_Float16)a.x, (_Float16)a.y, (_Float16)a.z, (_Float16)a.w,
             (_Float16)b.x, (_Float16)b.y, (_Float16)b.z, (_Float16)b.w};
  return h;
}

// Async global->LDS, 16 B/lane. LDS dest is wave-uniform base + lane*16.
__device__ __forceinline__ void gl16(const _Float16* g, _Float16* l) {
  __builtin_amdgcn_global_load_lds(
      (const __attribute__((address_space(1))) void*)g,
      (__attribute__((address_space(3))) void*)l, 16, 0, 0);
}

// ---------------- K1: everything independent, one launch. 256 threads.
// blk [0,256):        M2 GEMM 64x64 tile (fp32 staged, converted inline)
// blk [256,258):      Ws1|Ws2 -> fp16
// blk [258,514):      wqbr = Wq @ br (fp32 + fp16 copies)
// blk [514,4610):     region -> fp16, rdvec = region.Ws0   (4 rows/block)
// blk [4610,6658):    query -> fp16, h1 = query.Ws1        (4 rows/block)
__global__ __launch_bounds__(256) void prep_all(
    const float* __restrict__ Wr, const float* __restrict__ Wq,
    const float* __restrict__ Ws, const float* __restrict__ br,
    const float* __restrict__ region, const float* __restrict__ query,
    _Float16* __restrict__ M2, _Float16* __restrict__ Ws16,
    float* __restrict__ wqbr, _Float16* __restrict__ wqbr16,
    _Float16* __restrict__ r16, float* __restrict__ rdvec,
    _Float16* __restrict__ q16, float* __restrict__ h1) {
  __shared__ __align__(16) _Float16 lds[2 * 2 * 2048];  // 16 KB (M2 path)
  const int blk = blockIdx.x, tid = threadIdx.x;

  if (blk < 256) {  // ---- M2 = NT(Wr, Wq), 64x64 tile, K=1024
    const int m0 = (blk >> 4) * 64, n0 = (blk & 15) * 64;
    const int lane = tid & 63, w = tid >> 6;
    const int wr = w >> 1, wc = w & 1;
    const int srow = tid >> 2, slot = tid & 3;
    const int scol = (slot ^ ((srow >> 1) & 3)) * 8;
    const long offA = (long)(m0 + srow) * DD + scol;
    const long offB = (long)(n0 + srow) * DD + scol;
    const int wofs = srow * 32 + slot * 8;
    const int NK = DD / 32;
    float4 a0, a1, b0, b1;
    a0 = *(const float4*)(Wr + offA); a1 = *(const float4*)(Wr + offA + 4);
    b0 = *(const float4*)(Wq + offB); b1 = *(const float4*)(Wq + offB + 4);
    *(int4*)&lds[wofs] = *(int4*)&(const half8&)cvt8(a0, a1);
    {
      half8 hb = cvt8(b0, b1);
      *(half8*)&lds[2048 + wofs] = hb;
    }
    a0 = *(const float4*)(Wr + offA + 32); a1 = *(const float4*)(Wr + offA + 36);
    b0 = *(const float4*)(Wq + offB + 32); b1 = *(const float4*)(Wq + offB + 36);
    __syncthreads();
    floatx4 acc[2][2] = {};
    const int fr = lane & 15, g = lane >> 4;
    const int fs = (g ^ ((fr >> 1) & 3)) * 8;
    for (int kt = 0; kt < NK; ++kt) {
      const int cur = (kt & 1) * 4096, nxt = ((kt + 1) & 1) * 4096;
      if (kt + 1 < NK) {
        half8 ha = cvt8(a0, a1), hb = cvt8(b0, b1);
        *(half8*)&lds[nxt + wofs] = ha;
        *(half8*)&lds[nxt + 2048 + wofs] = hb;
      }
      if (kt + 2 < NK) {
        const long go = (long)(kt + 2) * 32;
        a0 = *(const float4*)(Wr + offA + go); a1 = *(const float4*)(Wr + offA + go + 4);
        b0 = *(const float4*)(Wq + offB + go); b1 = *(const float4*)(Wq + offB + go + 4);
      }
      half8 af[2], bf[2];
#pragma unroll
      for (int i = 0; i < 2; ++i)
        af[i] = *(const half8*)&lds[cur + (32 * wr + 16 * i + fr) * 32 + fs];
#pragma unroll
      for (int j = 0; j < 2; ++j)
        bf[j] = *(const half8*)&lds[cur + 2048 + (32 * wc + 16 * j + fr) * 32 + fs];
#pragma unroll
      for (int i = 0; i < 2; ++i)
#pragma unroll
        for (int j = 0; j < 2; ++j)
          acc[i][j] = __builtin_amdgcn_mfma_f32_16x16x32_f16(af[i], bf[j], acc[i][j], 0, 0, 0);
      __syncthreads();
    }
    const int cr = g * 4, cc = fr;
#pragma unroll
    for (int i = 0; i < 2; ++i)
#pragma unroll
      for (int r = 0; r < 4; ++r)
#pragma unroll
        for (int j = 0; j < 2; ++j)
          M2[(long)(m0 + 32 * wr + 16 * i + cr + r) * DD + n0 + 32 * wc + 16 * j + cc] =
              (_Float16)acc[i][j][r];
  } else if (blk < 258) {  // ---- Ws1|Ws2
    const long i = (long)(blk - 256) * 1024 + tid * 4;
    const float4 v = *(const float4*)&Ws[DD + i];
    half4 h = {(_Float16)v.x, (_Float16)v.y, (_Float16)v.z, (_Float16)v.w};
    *(half4*)&Ws16[i] = h;
  } else if (blk < 514) {  // ---- wqbr = Wq @ br
    const int row = (blk - 258) * 4 + (tid >> 6);
    const int lane = tid & 63;
    const float* x = Wq + (long)row * DD;
    float s = 0.f;
    for (int k = lane; k < DD; k += 64) s += x[k] * br[k];
    s = wave_sum(s);
    if (lane == 0) {
      wqbr[row] = s;
      wqbr16[row] = (_Float16)s;
    }
  } else if (blk < 514 + BR / 4) {  // ---- region conv + rdvec, wave-per-row
    const int wid = tid >> 6, lane = tid & 63;
    const long row = (long)(blk - 514) * 4 + wid;
    const float* src = region + row * DD;
    _Float16* dst = r16 + row * DD;
    float rd = 0.f;
#pragma unroll
    for (int it = 0; it < 4; ++it) {
      const int c = it * 256 + lane * 4;
      const float4 v = *(const float4*)&src[c];
      const float4 w0 = *(const float4*)&Ws[c];
      half4 h = {(_Float16)v.x, (_Float16)v.y, (_Float16)v.z, (_Float16)v.w};
      *(half4*)&dst[c] = h;
      rd += v.x * w0.x + v.y * w0.y + v.z * w0.z + v.w * w0.w;
    }
    rd = wave_sum(rd);
    if (lane == 0) rdvec[row] = rd;
  } else {  // ---- query conv + h1 = q.Ws1, wave-per-row
    const int wid = tid >> 6, lane = tid & 63;
    const long row = (long)(blk - (514 + BR / 4)) * 4 + wid;
    const float* src = query + row * DD;
    _Float16* dst = q16 + row * DD;
    float hq = 0.f;
#pragma unroll
    for (int it = 0; it < 4; ++it) {
      const int c = it * 256 + lane * 4;
      const float4 v = *(const float4*)&src[c];
      const float4 w1 = *(const float4*)&Ws[DD + c];
      half4 h = {(_Float16)v.x, (_Float16)v.y, (_Float16)v.z, (_Float16)v.w};
      *(half4*)&dst[c] = h;
      hq += v.x * w1.x + v.y * w1.y + v.z * w1.z + v.w * w1.w;
    }
    hq = wave_sum(hq);
    if (lane == 0) h1[row] = hq;
  }
}

// ---------------- K2: Qp = NT(query16, M2) — unchanged this round.
__global__ __launch_bounds__(512, 4) void qp_gemm(
    const _Float16* __restrict__ A, const _Float16* __restrict__ B,
    _Float16* __restrict__ C, const _Float16* __restrict__ wq16,
    float* __restrict__ cvec) {
  __shared__ __align__(16) _Float16 lds[2 * 2 * 4096];  // 32 KB
  const int lin = blockIdx.x;
  const int s = lin & 7, u = lin >> 3;  // XCD s owns m-strip [8s, 8s+8)
  const int mt = s * 8 + (u >> 3), nt = u & 7;
  const int m0 = mt * 128, n0 = nt * 128;
  const int tid = threadIdx.x, lane = tid & 63, w = tid >> 6;
  const int wr = w >> 1, wc = w & 1;

  const int lrow = lane >> 2, slot = lane & 3;
  const int scol = (slot ^ ((lrow >> 1) & 3)) * 8;
  const int srow = 16 * w + lrow;  // 0..127
  const _Float16* gA = A + (long)(m0 + srow) * DD + scol;
  const _Float16* gB = B + (long)(n0 + srow) * DD + scol;
  const int wbase = 512 * w;  // halfs: lane l lands at wbase + 8*l

  gl16(gA, &lds[wbase]);
  gl16(gB, &lds[4096 + wbase]);
  __syncthreads();

  floatx4 acc[2][4] = {};
  float cvp[2] = {0.f, 0.f};
  const int fr = lane & 15, g = lane >> 4;
  const int fs = (g ^ ((fr >> 1) & 3)) * 8;
  const int NK = DD / 32;

  for (int kt = 0; kt < NK; ++kt) {
    const int cur = (kt & 1) * 8192, nxt = cur ^ 8192;
    if (kt + 1 < NK) {
      const long go = (long)(kt + 1) * 32;
      gl16(gA + go, &lds[nxt + wbase]);
      gl16(gB + go, &lds[nxt + 4096 + wbase]);
    }
    half8 af[2], bf[4];
#pragma unroll
    for (int i = 0; i < 2; ++i)
      af[i] = *(const half8*)&lds[cur + (32 * wr + 16 * i + fr) * 32 + fs];
#pragma unroll
    for (int j = 0; j < 4; ++j)
      bf[j] = *(const half8*)&lds[cur + 4096 + (64 * wc + 16 * j + fr) * 32 + fs];
    if (wc == 0) {  // cvec partials: rows 32*wr+16*i+fr, cols kt*32+g*8
      const half8 wb = *(const half8*)&wq16[kt * 32 + g * 8];
#pragma unroll
      for (int i = 0; i < 2; ++i)
#pragma unroll
        for (int e = 0; e < 8; ++e)
          cvp[i] += (float)af[i][e] * (float)wb[e];
    }
#pragma unroll
    for (int i = 0; i < 2; ++i)
#pragma unroll
      for (int j = 0; j < 4; ++j)
        acc[i][j] = __builtin_amdgcn_mfma_f32_16x16x32_f16(af[i], bf[j], acc[i][j], 0, 0, 0);
    __syncthreads();
  }

  if (wc == 0 && nt == 0) {
#pragma unroll
    for (int i = 0; i < 2; ++i) {
      float c = cvp[i];
      c += __shfl_xor(c, 16);
      c += __shfl_xor(c, 32);
      if (lane < 16) cvec[m0 + 32 * wr + 16 * i + lane] = c;
    }
  }

  const int cr = g * 4, cc = fr;
#pragma unroll
  for (int i = 0; i < 2; ++i)
#pragma unroll
    for (int r = 0; r < 4; ++r)
#pragma unroll
      for (int j = 0; j < 4; ++j)
        C[(long)(m0 + 32 * wr + 16 * i + cr + r) * DD + n0 + 64 * wc + 16 * j + cc] =
            (_Float16)acc[i][j][r];
}

// ---------------- K3: fused S/H GEMM + split-softmax stats.
// 512 thr = 8 waves in 2(m) x 4(n); wave 64x32. Counted-vmcnt phase schedule:
// 4 half-slots (K=32 each), 3-half prefetch, 2 raw barriers per half,
// setprio(1) around the 16-MFMA cluster. Addressing identical to r9.
#define STAGE3(hh, sl)                                    \
  {                                                       \
    const long go_ = (long)(hh) * 32;                     \
    gl16(gA + go_, &lds[(sl) * 12288 + wbase]);           \
    gl16(gP + go_, &lds[(sl) * 12288 + 4096 + wbase]);    \
    gl16(gQ + go_, &lds[(sl) * 12288 + 8192 + wbase]);    \
  }

#define HALFSTEP(h, sl, VM)                                                    \
  {                                                                            \
    asm volatile("s_waitcnt vmcnt(" #VM ")" ::: "memory");                     \
    __builtin_amdgcn_s_barrier();                                              \
    asm volatile("" ::: "memory");                                             \
    half8 af[4], bp[2], bq[2];                                                 \
    _Pragma("unroll") for (int i = 0; i < 4; ++i)                              \
      af[i] = *(const half8*)&lds[(sl) * 12288 + (64 * wr + 16 * i + fr) * 32 + fs]; \
    _Pragma("unroll") for (int j = 0; j < 2; ++j)                              \
      bp[j] = *(const half8*)&lds[(sl) * 12288 + 4096 + (32 * wc + 16 * j + fr) * 32 + fs]; \
    _Pragma("unroll") for (int j = 0; j < 2; ++j)                              \
      bq[j] = *(const half8*)&lds[(sl) * 12288 + 8192 + (32 * wc + 16 * j + fr) * 32 + fs]; \
    const half8 w2f = *(const half8*)&wlds[(h) * 32 + g * 8];                  \
    bq[0] *= w2f;                                                              \
    bq[1] *= w2f;                                                              \
    __builtin_amdgcn_s_setprio(1);                                             \
    _Pragma("unroll") for (int i = 0; i < 4; ++i)                              \
      _Pragma("unroll") for (int j = 0; j < 2; ++j)                            \
        accS[i][j] = __builtin_amdgcn_mfma_f32_16x16x32_f16(af[i], bp[j], accS[i][j], 0, 0, 0); \
    _Pragma("unroll") for (int i = 0; i < 4; ++i)                              \
      _Pragma("unroll") for (int j = 0; j < 2; ++j)                            \
        accH[i][j] = __builtin_amdgcn_mfma_f32_16x16x32_f16(af[i], bq[j], accH[i][j], 0, 0, 0); \
    __builtin_amdgcn_s_setprio(0);                                             \
    __builtin_amdgcn_s_barrier();                                              \
    asm volatile("" ::: "memory");                                             \
  }

__global__ __launch_bounds__(512, 2) void gemm_fused(
    const _Float16* __restrict__ A, const _Float16* __restrict__ B0,
    const _Float16* __restrict__ B1,
    float* __restrict__ Ms, float* __restrict__ Ls, float* __restrict__ Hs,
    const float* __restrict__ cvec, const float* __restrict__ h1,
    const _Float16* __restrict__ wsh, long sA, long sB) {
  __shared__ __align__(16) _Float16 lds[4 * 12288];  // 96 KB: 4 half-slots
  __shared__ __align__(16) _Float16 wlds[1024];      // Ws2

  const int lin = blockIdx.x;
  const int s = lin & 7, u = lin >> 3;  // XCD s owns batches 2s, 2s+1
  const int b = 2 * s + (u >> 5);
  const int t = u & 31;
  const int mt = t >> 2, nt = t & 3;
  const int m0 = mt * 128, n0 = nt * 128;
  A += (long)b * sA;
  B0 += (long)b * sB;
  B1 += (long)b * sB;

  const int tid = threadIdx.x, lane = tid & 63, w = tid >> 6;
  const int wr = w >> 2, wc = w & 3;  // 2 x 4

  const int lrow = lane >> 2, slot = lane & 3;
  const int scol = (slot ^ ((lrow >> 1) & 3)) * 8;
  const int srow = 16 * w + lrow;  // 0..127
  const _Float16* gA = A + (long)(m0 + srow) * DD + scol;
  const _Float16* gP = B0 + (long)(n0 + srow) * DD + scol;
  const _Float16* gQ = B1 + (long)(n0 + srow) * DD + scol;
  const int wbase = 512 * w;

  if (tid < 128) *(int4*)&wlds[tid * 8] = *(const int4*)&wsh[1024 + tid * 8];
  __syncthreads();  // drains the wlds load+write; clean vmcnt slate

  floatx4 accS[4][2] = {};
  floatx4 accH[4][2] = {};
  const int fr = lane & 15, g = lane >> 4;
  const int fs = (g ^ ((fr >> 1) & 3)) * 8;

  // prologue: 3 halves in flight (9 gl16 / lane)
  STAGE3(0, 0);
  STAGE3(1, 1);
  STAGE3(2, 2);

  for (int hb = 0; hb < 28; hb += 4) {
    STAGE3(hb + 3, 3); HALFSTEP(hb + 0, 0, 9);
    STAGE3(hb + 4, 0); HALFSTEP(hb + 1, 1, 9);
    STAGE3(hb + 5, 1); HALFSTEP(hb + 2, 2, 9);
    STAGE3(hb + 6, 2); HALFSTEP(hb + 3, 3, 9);
  }
  STAGE3(31, 3); HALFSTEP(28, 0, 9);
  HALFSTEP(29, 1, 6);
  HALFSTEP(30, 2, 3);
  HALFSTEP(31, 3, 0);

  // C/D layout: col = lane&15, row = g*4 + reg.
  const int cr = g * 4, cc = fr;
  float cv[2], hv[2];
#pragma unroll
  for (int j = 0; j < 2; ++j) {
    const long col = (long)b * TD + n0 + 32 * wc + 16 * j + cc;
    cv[j] = cvec[col];
    hv[j] = h1[col];
  }
  const int chunk = nt * 4 + wc;  // 32-col chunk 0..15
  const long rowBase = (long)b * RD + m0 + 64 * wr + cr;
#pragma unroll
  for (int i = 0; i < 4; ++i) {
#pragma unroll
    for (int r = 0; r < 4; ++r) {
      float mx = fmaxf(accS[i][0][r] + cv[0], accS[i][1][r] + cv[1]);
      mx = fmaxf(mx, __shfl_xor(mx, 1));
      mx = fmaxf(mx, __shfl_xor(mx, 2));
      mx = fmaxf(mx, __shfl_xor(mx, 4));
      mx = fmaxf(mx, __shfl_xor(mx, 8));
      float l = 0.f, hs = 0.f;
#pragma unroll
      for (int j = 0; j < 2; ++j) {
        const float e = __expf(accS[i][j][r] + cv[j] - mx);
        l += e;
        hs += e * (accH[i][j][r] + hv[j]);
      }
      l += __shfl_xor(l, 1); hs += __shfl_xor(hs, 1);
      l += __shfl_xor(l, 2); hs += __shfl_xor(hs, 2);
      l += __shfl_xor(l, 4); hs += __shfl_xor(hs, 4);
      l += __shfl_xor(l, 8); hs += __shfl_xor(hs, 8);
      if (cc == 0) {
        const long idx = (long)chunk * BR + rowBase + 16 * i + r;
        Ms[idx] = mx;
        Ls[idx] = l;
        Hs[idx] = hs;
      }
    }
  }
}

// ---------------- K4: combine 16 chunk-stats per row.
__global__ __launch_bounds__(256) void combine(
    const float* __restrict__ Ms, const float* __restrict__ Ls,
    const float* __restrict__ Hs, const float* __restrict__ rdvec,
    const float* __restrict__ bs, float* __restrict__ out) {
  const int row = blockIdx.x * 256 + threadIdx.x;
  float mv[16];
  float gm = -1e30f;
#pragma unroll
  for (int c = 0; c < 16; ++c) {
    mv[c] = Ms[(long)c * BR + row];
    gm = fmaxf(gm, mv[c]);
  }
  float L = 0.f, HS = 0.f;
#pragma unroll
  for (int c = 0; c < 16; ++c) {
    const float sc = __expf(mv[c] - gm);
    L += Ls[(long)c * BR + row] * sc;
    HS += Hs[(long)c * BR + row] * sc;
  }
  out[row] = HS / L + rdvec[row] + bs[0];
}

extern "C" void kernel_launch(void* const* d_in, const int* in_sizes, int n_in,
                              void* d_out, int out_size, void* d_ws, size_t ws_size,
                              hipStream_t stream) {
  const float* region = (const float*)d_in[0];
  const float* query  = (const float*)d_in[1];
  const float* Wr     = (const float*)d_in[2];
  const float* br     = (const float*)d_in[3];
  const float* Wq     = (const float*)d_in[4];
  // d_in[5] = bq: t-constant per score row, cancels in softmax.
  const float* Ws     = (const float*)d_in[6];
  const float* bs     = (const float*)d_in[7];
  float* out = (float*)d_out;

  // ws layout (~70 MiB; <= proven-safe 74 MiB).
  char* p = (char*)d_ws;
  _Float16* region16 = (_Float16*)p;                   // 32 MiB
  _Float16* query16  = (_Float16*)(p + (32u << 20));   // 16 MiB
  _Float16* Qp       = (_Float16*)(p + (48u << 20));   // 16 MiB
  _Float16* M2       = (_Float16*)(p + (64u << 20));   // 2 MiB
  _Float16* Ws16     = (_Float16*)(p + (66u << 20));   // 4 KiB (Ws1|Ws2)
  float*    wqbr     = (float*)(p + (66u << 20) + 8192);    // 4 KiB
  _Float16* wqbr16   = (_Float16*)(p + (66u << 20) + 12288);// 2 KiB
  float*    cvec     = (float*)(p + (66u << 20) + 16384);   // 32 KiB
  float*    rdvec    = (float*)(p + (66u << 20) + 65536);   // 64 KiB
  float*    h1       = (float*)(p + (66u << 20) + 131072);  // 32 KiB
  float*    Ms       = (float*)(p + (67u << 20));      // 3 x 1 MiB stats
  float*    Ls       = Ms + 16 * BR;
  float*    Hs       = Ls + 16 * BR;

  // K1: M2 GEMM + all conversions + wqbr + rdvec + h1, one launch.
  prep_all<<<dim3(514 + BR / 4 + BD * TD / 4), 256, 0, stream>>>(
      Wr, Wq, Ws, br, region, query, M2, Ws16, wqbr, wqbr16,
      region16, rdvec, query16, h1);
  // K2: Qp = NT(query16, M2) + cvec epilogue.
  qp_gemm<<<dim3(512), 512, 0, stream>>>(query16, M2, Qp, wqbr16, cvec);
  // K3: fused S/H + split-softmax stats (counted-vmcnt schedule).
  gemm_fused<<<dim3(512), 512, 0, stream>>>(
      region16, Qp, query16, Ms, Ls, Hs, cvec, h1, Ws16,
      (long)RD * DD, (long)TD * DD);
  // K4: out = HS/L + region.Ws0 + bs.
  combine<<<dim3(BR / 256), 256, 0, stream>>>(Ms, Ls, Hs, rdvec, bs, out);
}

// Round 3
// 216.546 us; speedup vs baseline: 1.0498x; 1.0498x over previous
//
#include <hip/hip_runtime.h>

// CrossModalAttentionScorer — round 11: counted-vmcnt redo with occupancy
// preserved. B=16, R=1024, T=512, D=H=1024.
//
// r10 failure analysis: 4 slots x 24KB = 96KB LDS -> 1 block/CU (occ 36->20%),
// 2 barriers/step, VGPR 88. The schedule never got to act.
// r11: 3-slot rotation (72KB + 2KB = 74KB -> 2 blocks/CU, same as r9),
// ONE trailing barrier/step, vmcnt(3) steady-state (never 0 until tail):
//   step h: STAGE(h+2 -> slot (h+2)%3) ; ds_read slot h%3 ; 16 MFMA ;
//           vmcnt(3) ; s_barrier
// Hazards: slot (h+2)%3 == (h-1)%3 last read before step h-1's trailing
// barrier; per-wave vmcnt before barrier makes all waves' h+1 data visible;
// ds_reads complete before their MFMAs (compiler lgkmcnt) so slot is free.
// K2 gets the same treatment (4 x 16KB slots, vmcnt(4)); its per-step wq16
// GLOBAL read moved to LDS (a global load inside the loop would break the
// vmcnt counting).

#define BD 16
#define RD 1024
#define TD 512
#define DD 1024
#define BR (BD * RD)

typedef _Float16 half8 __attribute__((ext_vector_type(8)));
typedef _Float16 half4 __attribute__((ext_vector_type(4)));
typedef float floatx4 __attribute__((ext_vector_type(4)));

__device__ __forceinline__ float wave_sum(float v) {
#pragma unroll
  for (int off = 32; off > 0; off >>= 1) v += __shfl_down(v, off);
  return v;
}

__device__ __forceinline__ half8 cvt8(float4 a, float4 b) {
  half8 h = {(_Float16)a.x, (_Float16)a.y, (_Float16)a.z, (_Float16)a.w,
             (_Float16)b.x, (_Float16)b.y, (_Float16)b.z, (_Float16)b.w};
  return h;
}

// Async global->LDS, 16 B/lane. LDS dest is wave-uniform base + lane*16.
__device__ __forceinline__ void gl16(const _Float16* g, _Float16* l) {
  __builtin_amdgcn_global_load_lds(
      (const __attribute__((address_space(1))) void*)g,
      (__attribute__((address_space(3))) void*)l, 16, 0, 0);
}

#define VMW_(N) asm volatile("s_waitcnt vmcnt(" #N ")" ::: "memory")
#define VMW(N) VMW_(N)
#define BARR                        \
  __builtin_amdgcn_s_barrier();     \
  asm volatile("" ::: "memory")

// ---------------- K1: everything independent, one launch. 256 threads.
// blk [0,256):        M2 GEMM 64x64 tile (fp32 staged, converted inline)
// blk [256,258):      Ws1|Ws2 -> fp16
// blk [258,514):      wqbr = Wq @ br (fp32 + fp16 copies)
// blk [514,4610):     region -> fp16, rdvec = region.Ws0   (4 rows/block)
// blk [4610,6658):    query -> fp16, h1 = query.Ws1        (4 rows/block)
__global__ __launch_bounds__(256) void prep_all(
    const float* __restrict__ Wr, const float* __restrict__ Wq,
    const float* __restrict__ Ws, const float* __restrict__ br,
    const float* __restrict__ region, const float* __restrict__ query,
    _Float16* __restrict__ M2, _Float16* __restrict__ Ws16,
    float* __restrict__ wqbr, _Float16* __restrict__ wqbr16,
    _Float16* __restrict__ r16, float* __restrict__ rdvec,
    _Float16* __restrict__ q16, float* __restrict__ h1) {
  __shared__ __align__(16) _Float16 lds[2 * 2 * 2048];  // 16 KB (M2 path)
  const int blk = blockIdx.x, tid = threadIdx.x;

  if (blk < 256) {  // ---- M2 = NT(Wr, Wq), 64x64 tile, K=1024
    const int m0 = (blk >> 4) * 64, n0 = (blk & 15) * 64;
    const int lane = tid & 63, w = tid >> 6;
    const int wr = w >> 1, wc = w & 1;
    const int srow = tid >> 2, slot = tid & 3;
    const int scol = (slot ^ ((srow >> 1) & 3)) * 8;
    const long offA = (long)(m0 + srow) * DD + scol;
    const long offB = (long)(n0 + srow) * DD + scol;
    const int wofs = srow * 32 + slot * 8;
    const int NK = DD / 32;
    float4 a0, a1, b0, b1;
    a0 = *(const float4*)(Wr + offA); a1 = *(const float4*)(Wr + offA + 4);
    b0 = *(const float4*)(Wq + offB); b1 = *(const float4*)(Wq + offB + 4);
    *(int4*)&lds[wofs] = *(int4*)&(const half8&)cvt8(a0, a1);
    {
      half8 hb = cvt8(b0, b1);
      *(half8*)&lds[2048 + wofs] = hb;
    }
    a0 = *(const float4*)(Wr + offA + 32); a1 = *(const float4*)(Wr + offA + 36);
    b0 = *(const float4*)(Wq + offB + 32); b1 = *(const float4*)(Wq + offB + 36);
    __syncthreads();
    floatx4 acc[2][2] = {};
    const int fr = lane & 15, g = lane >> 4;
    const int fs = (g ^ ((fr >> 1) & 3)) * 8;
    for (int kt = 0; kt < NK; ++kt) {
      const int cur = (kt & 1) * 4096, nxt = ((kt + 1) & 1) * 4096;
      if (kt + 1 < NK) {
        half8 ha = cvt8(a0, a1), hb = cvt8(b0, b1);
        *(half8*)&lds[nxt + wofs] = ha;
        *(half8*)&lds[nxt + 2048 + wofs] = hb;
      }
      if (kt + 2 < NK) {
        const long go = (long)(kt + 2) * 32;
        a0 = *(const float4*)(Wr + offA + go); a1 = *(const float4*)(Wr + offA + go + 4);
        b0 = *(const float4*)(Wq + offB + go); b1 = *(const float4*)(Wq + offB + go + 4);
      }
      half8 af[2], bf[2];
#pragma unroll
      for (int i = 0; i < 2; ++i)
        af[i] = *(const half8*)&lds[cur + (32 * wr + 16 * i + fr) * 32 + fs];
#pragma unroll
      for (int j = 0; j < 2; ++j)
        bf[j] = *(const half8*)&lds[cur + 2048 + (32 * wc + 16 * j + fr) * 32 + fs];
#pragma unroll
      for (int i = 0; i < 2; ++i)
#pragma unroll
        for (int j = 0; j < 2; ++j)
          acc[i][j] = __builtin_amdgcn_mfma_f32_16x16x32_f16(af[i], bf[j], acc[i][j], 0, 0, 0);
      __syncthreads();
    }
    const int cr = g * 4, cc = fr;
#pragma unroll
    for (int i = 0; i < 2; ++i)
#pragma unroll
      for (int r = 0; r < 4; ++r)
#pragma unroll
        for (int j = 0; j < 2; ++j)
          M2[(long)(m0 + 32 * wr + 16 * i + cr + r) * DD + n0 + 32 * wc + 16 * j + cc] =
              (_Float16)acc[i][j][r];
  } else if (blk < 258) {  // ---- Ws1|Ws2
    const long i = (long)(blk - 256) * 1024 + tid * 4;
    const float4 v = *(const float4*)&Ws[DD + i];
    half4 h = {(_Float16)v.x, (_Float16)v.y, (_Float16)v.z, (_Float16)v.w};
    *(half4*)&Ws16[i] = h;
  } else if (blk < 514) {  // ---- wqbr = Wq @ br
    const int row = (blk - 258) * 4 + (tid >> 6);
    const int lane = tid & 63;
    const float* x = Wq + (long)row * DD;
    float s = 0.f;
    for (int k = lane; k < DD; k += 64) s += x[k] * br[k];
    s = wave_sum(s);
    if (lane == 0) {
      wqbr[row] = s;
      wqbr16[row] = (_Float16)s;
    }
  } else if (blk < 514 + BR / 4) {  // ---- region conv + rdvec, wave-per-row
    const int wid = tid >> 6, lane = tid & 63;
    const long row = (long)(blk - 514) * 4 + wid;
    const float* src = region + row * DD;
    _Float16* dst = r16 + row * DD;
    float rd = 0.f;
#pragma unroll
    for (int it = 0; it < 4; ++it) {
      const int c = it * 256 + lane * 4;
      const float4 v = *(const float4*)&src[c];
      const float4 w0 = *(const float4*)&Ws[c];
      half4 h = {(_Float16)v.x, (_Float16)v.y, (_Float16)v.z, (_Float16)v.w};
      *(half4*)&dst[c] = h;
      rd += v.x * w0.x + v.y * w0.y + v.z * w0.z + v.w * w0.w;
    }
    rd = wave_sum(rd);
    if (lane == 0) rdvec[row] = rd;
  } else {  // ---- query conv + h1 = q.Ws1, wave-per-row
    const int wid = tid >> 6, lane = tid & 63;
    const long row = (long)(blk - (514 + BR / 4)) * 4 + wid;
    const float* src = query + row * DD;
    _Float16* dst = q16 + row * DD;
    float hq = 0.f;
#pragma unroll
    for (int it = 0; it < 4; ++it) {
      const int c = it * 256 + lane * 4;
      const float4 v = *(const float4*)&src[c];
      const float4 w1 = *(const float4*)&Ws[DD + c];
      half4 h = {(_Float16)v.x, (_Float16)v.y, (_Float16)v.z, (_Float16)v.w};
      *(half4*)&dst[c] = h;
      hq += v.x * w1.x + v.y * w1.y + v.z * w1.z + v.w * w1.w;
    }
    hq = wave_sum(hq);
    if (lane == 0) h1[row] = hq;
  }
}

// ---------------- K2: Qp = NT(query16, M2) — 512thr/128x128, wave 32x64.
// 4-slot (16 KB each) counted-vmcnt schedule: step h stages h+3, computes h,
// trailing vmcnt(4)+barrier. wq16 staged to LDS (global load in-loop would
// break vmcnt counting).
#define STAGE2(hh, sl)                                  \
  {                                                     \
    const long go_ = (long)(hh) * 32;                   \
    gl16(gA + go_, &lds[(sl) * 8192 + wbase]);          \
    gl16(gB + go_, &lds[(sl) * 8192 + 4096 + wbase]);   \
  }

#define COMP2(h, sl)                                                           \
  {                                                                            \
    half8 af[2], bf[4];                                                        \
    _Pragma("unroll") for (int i = 0; i < 2; ++i)                              \
      af[i] = *(const half8*)&lds[(sl) * 8192 + (32 * wr + 16 * i + fr) * 32 + fs]; \
    _Pragma("unroll") for (int j = 0; j < 4; ++j)                              \
      bf[j] = *(const half8*)&lds[(sl) * 8192 + 4096 + (64 * wc + 16 * j + fr) * 32 + fs]; \
    if (wc == 0) {                                                             \
      const half8 wb = *(const half8*)&wq_lds[(h) * 32 + g * 8];               \
      _Pragma("unroll") for (int i = 0; i < 2; ++i)                            \
        _Pragma("unroll") for (int e = 0; e < 8; ++e)                          \
          cvp[i] += (float)af[i][e] * (float)wb[e];                            \
    }                                                                          \
    __builtin_amdgcn_s_setprio(1);                                             \
    _Pragma("unroll") for (int i = 0; i < 2; ++i)                              \
      _Pragma("unroll") for (int j = 0; j < 4; ++j)                            \
        acc[i][j] = __builtin_amdgcn_mfma_f32_16x16x32_f16(af[i], bf[j], acc[i][j], 0, 0, 0); \
    __builtin_amdgcn_s_setprio(0);                                             \
  }

__global__ __launch_bounds__(512, 4) void qp_gemm(
    const _Float16* __restrict__ A, const _Float16* __restrict__ B,
    _Float16* __restrict__ C, const _Float16* __restrict__ wq16,
    float* __restrict__ cvec) {
  __shared__ __align__(16) _Float16 lds[4 * 8192];   // 64 KB: 4 slots
  __shared__ __align__(16) _Float16 wq_lds[1024];
  const int lin = blockIdx.x;
  const int s = lin & 7, u = lin >> 3;  // XCD s owns m-strip [8s, 8s+8)
  const int mt = s * 8 + (u >> 3), nt = u & 7;
  const int m0 = mt * 128, n0 = nt * 128;
  const int tid = threadIdx.x, lane = tid & 63, w = tid >> 6;
  const int wr = w >> 1, wc = w & 1;

  const int lrow = lane >> 2, slot = lane & 3;
  const int scol = (slot ^ ((lrow >> 1) & 3)) * 8;
  const int srow = 16 * w + lrow;  // 0..127
  const _Float16* gA = A + (long)(m0 + srow) * DD + scol;
  const _Float16* gB = B + (long)(n0 + srow) * DD + scol;
  const int wbase = 512 * w;  // halfs: lane l lands at wbase + 8*l

  if (tid < 128) *(int4*)&wq_lds[tid * 8] = *(const int4*)&wq16[tid * 8];
  __syncthreads();  // wq_lds visible; clean vmcnt slate

  floatx4 acc[2][4] = {};
  float cvp[2] = {0.f, 0.f};
  const int fr = lane & 15, g = lane >> 4;
  const int fs = (g ^ ((fr >> 1) & 3)) * 8;

  STAGE2(0, 0); STAGE2(1, 1); STAGE2(2, 2);  // 6 outstanding
  VMW(4); BARR;                              // slot 0 landed everywhere

  for (int hb = 0; hb < 28; hb += 4) {
    STAGE2(hb + 3, 3); COMP2(hb + 0, 0); VMW(4); BARR;
    STAGE2(hb + 4, 0); COMP2(hb + 1, 1); VMW(4); BARR;
    STAGE2(hb + 5, 1); COMP2(hb + 2, 2); VMW(4); BARR;
    STAGE2(hb + 6, 2); COMP2(hb + 3, 3); VMW(4); BARR;
  }
  STAGE2(31, 3); COMP2(28, 0); VMW(4); BARR;
  COMP2(29, 1); VMW(2); BARR;
  COMP2(30, 2); VMW(0); BARR;
  COMP2(31, 3);

  if (wc == 0 && nt == 0) {
#pragma unroll
    for (int i = 0; i < 2; ++i) {
      float c = cvp[i];
      c += __shfl_xor(c, 16);
      c += __shfl_xor(c, 32);
      if (lane < 16) cvec[m0 + 32 * wr + 16 * i + lane] = c;
    }
  }

  const int cr = g * 4, cc = fr;
#pragma unroll
  for (int i = 0; i < 2; ++i)
#pragma unroll
    for (int r = 0; r < 4; ++r)
#pragma unroll
      for (int j = 0; j < 4; ++j)
        C[(long)(m0 + 32 * wr + 16 * i + cr + r) * DD + n0 + 64 * wc + 16 * j + cc] =
            (_Float16)acc[i][j][r];
}

// ---------------- K3: fused S/H GEMM + split-softmax stats.
// 512 thr = 8 waves in 2(m) x 4(n); wave 64x32. 3-slot (24 KB each) rotation,
// 2-step prefetch, ONE trailing vmcnt(3)+barrier per step, setprio around the
// 16-MFMA cluster. LDS 74 KB -> 2 blocks/CU (grid-limited anyway).
#define STAGE3(hh, sl)                                    \
  {                                                       \
    const long go_ = (long)(hh) * 32;                     \
    gl16(gA + go_, &lds[(sl) * 12288 + wbase]);           \
    gl16(gP + go_, &lds[(sl) * 12288 + 4096 + wbase]);    \
    gl16(gQ + go_, &lds[(sl) * 12288 + 8192 + wbase]);    \
  }

#define COMP3(h, sl)                                                           \
  {                                                                            \
    half8 af[4], bp[2], bq[2];                                                 \
    _Pragma("unroll") for (int i = 0; i < 4; ++i)                              \
      af[i] = *(const half8*)&lds[(sl) * 12288 + (64 * wr + 16 * i + fr) * 32 + fs]; \
    _Pragma("unroll") for (int j = 0; j < 2; ++j)                              \
      bp[j] = *(const half8*)&lds[(sl) * 12288 + 4096 + (32 * wc + 16 * j + fr) * 32 + fs]; \
    _Pragma("unroll") for (int j = 0; j < 2; ++j)                              \
      bq[j] = *(const half8*)&lds[(sl) * 12288 + 8192 + (32 * wc + 16 * j + fr) * 32 + fs]; \
    const half8 w2f = *(const half8*)&wlds[(h) * 32 + g * 8];                  \
    bq[0] *= w2f;                                                              \
    bq[1] *= w2f;                                                              \
    __builtin_amdgcn_s_setprio(1);                                             \
    _Pragma("unroll") for (int i = 0; i < 4; ++i)                              \
      _Pragma("unroll") for (int j = 0; j < 2; ++j)                            \
        accS[i][j] = __builtin_amdgcn_mfma_f32_16x16x32_f16(af[i], bp[j], accS[i][j], 0, 0, 0); \
    _Pragma("unroll") for (int i = 0; i < 4; ++i)                              \
      _Pragma("unroll") for (int j = 0; j < 2; ++j)                            \
        accH[i][j] = __builtin_amdgcn_mfma_f32_16x16x32_f16(af[i], bq[j], accH[i][j], 0, 0, 0); \
    __builtin_amdgcn_s_setprio(0);                                             \
  }

__global__ __launch_bounds__(512, 4) void gemm_fused(
    const _Float16* __restrict__ A, const _Float16* __restrict__ B0,
    const _Float16* __restrict__ B1,
    float* __restrict__ Ms, float* __restrict__ Ls, float* __restrict__ Hs,
    const float* __restrict__ cvec, const float* __restrict__ h1,
    const _Float16* __restrict__ wsh, long sA, long sB) {
  __shared__ __align__(16) _Float16 lds[3 * 12288];  // 72 KB: 3 slots
  __shared__ __align__(16) _Float16 wlds[1024];      // Ws2

  const int lin = blockIdx.x;
  const int s = lin & 7, u = lin >> 3;  // XCD s owns batches 2s, 2s+1
  const int b = 2 * s + (u >> 5);
  const int t = u & 31;
  const int mt = t >> 2, nt = t & 3;
  const int m0 = mt * 128, n0 = nt * 128;
  A += (long)b * sA;
  B0 += (long)b * sB;
  B1 += (long)b * sB;

  const int tid = threadIdx.x, lane = tid & 63, w = tid >> 6;
  const int wr = w >> 2, wc = w & 3;  // 2 x 4

  const int lrow = lane >> 2, slot = lane & 3;
  const int scol = (slot ^ ((lrow >> 1) & 3)) * 8;
  const int srow = 16 * w + lrow;  // 0..127
  const _Float16* gA = A + (long)(m0 + srow) * DD + scol;
  const _Float16* gP = B0 + (long)(n0 + srow) * DD + scol;
  const _Float16* gQ = B1 + (long)(n0 + srow) * DD + scol;
  const int wbase = 512 * w;

  if (tid < 128) *(int4*)&wlds[tid * 8] = *(const int4*)&wsh[1024 + tid * 8];
  __syncthreads();  // wlds visible; clean vmcnt slate

  floatx4 accS[4][2] = {};
  floatx4 accH[4][2] = {};
  const int fr = lane & 15, g = lane >> 4;
  const int fs = (g ^ ((fr >> 1) & 3)) * 8;

  STAGE3(0, 0); STAGE3(1, 1);  // 6 outstanding
  VMW(3); BARR;                // slot 0 landed everywhere

  for (int hb = 0; hb < 30; hb += 3) {
    STAGE3(hb + 2, 2); COMP3(hb + 0, 0); VMW(3); BARR;
    STAGE3(hb + 3, 0); COMP3(hb + 1, 1); VMW(3); BARR;
    STAGE3(hb + 4, 1); COMP3(hb + 2, 2); VMW(3); BARR;
  }
  COMP3(30, 0); VMW(0); BARR;
  COMP3(31, 1);

  // C/D layout: col = lane&15, row = g*4 + reg.
  const int cr = g * 4, cc = fr;
  float cv[2], hv[2];
#pragma unroll
  for (int j = 0; j < 2; ++j) {
    const long col = (long)b * TD + n0 + 32 * wc + 16 * j + cc;
    cv[j] = cvec[col];
    hv[j] = h1[col];
  }
  const int chunk = nt * 4 + wc;  // 32-col chunk 0..15
  const long rowBase = (long)b * RD + m0 + 64 * wr + cr;
#pragma unroll
  for (int i = 0; i < 4; ++i) {
#pragma unroll
    for (int r = 0; r < 4; ++r) {
      float mx = fmaxf(accS[i][0][r] + cv[0], accS[i][1][r] + cv[1]);
      mx = fmaxf(mx, __shfl_xor(mx, 1));
      mx = fmaxf(mx, __shfl_xor(mx, 2));
      mx = fmaxf(mx, __shfl_xor(mx, 4));
      mx = fmaxf(mx, __shfl_xor(mx, 8));
      float l = 0.f, hs = 0.f;
#pragma unroll
      for (int j = 0; j < 2; ++j) {
        const float e = __expf(accS[i][j][r] + cv[j] - mx);
        l += e;
        hs += e * (accH[i][j][r] + hv[j]);
      }
      l += __shfl_xor(l, 1); hs += __shfl_xor(hs, 1);
      l += __shfl_xor(l, 2); hs += __shfl_xor(hs, 2);
      l += __shfl_xor(l, 4); hs += __shfl_xor(hs, 4);
      l += __shfl_xor(l, 8); hs += __shfl_xor(hs, 8);
      if (cc == 0) {
        const long idx = (long)chunk * BR + rowBase + 16 * i + r;
        Ms[idx] = mx;
        Ls[idx] = l;
        Hs[idx] = hs;
      }
    }
  }
}

// ---------------- K4: combine 16 chunk-stats per row.
__global__ __launch_bounds__(256) void combine(
    const float* __restrict__ Ms, const float* __restrict__ Ls,
    const float* __restrict__ Hs, const float* __restrict__ rdvec,
    const float* __restrict__ bs, float* __restrict__ out) {
  const int row = blockIdx.x * 256 + threadIdx.x;
  float mv[16];
  float gm = -1e30f;
#pragma unroll
  for (int c = 0; c < 16; ++c) {
    mv[c] = Ms[(long)c * BR + row];
    gm = fmaxf(gm, mv[c]);
  }
  float L = 0.f, HS = 0.f;
#pragma unroll
  for (int c = 0; c < 16; ++c) {
    const float sc = __expf(mv[c] - gm);
    L += Ls[(long)c * BR + row] * sc;
    HS += Hs[(long)c * BR + row] * sc;
  }
  out[row] = HS / L + rdvec[row] + bs[0];
}

extern "C" void kernel_launch(void* const* d_in, const int* in_sizes, int n_in,
                              void* d_out, int out_size, void* d_ws, size_t ws_size,
                              hipStream_t stream) {
  const float* region = (const float*)d_in[0];
  const float* query  = (const float*)d_in[1];
  const float* Wr     = (const float*)d_in[2];
  const float* br     = (const float*)d_in[3];
  const float* Wq     = (const float*)d_in[4];
  // d_in[5] = bq: t-constant per score row, cancels in softmax.
  const float* Ws     = (const float*)d_in[6];
  const float* bs     = (const float*)d_in[7];
  float* out = (float*)d_out;

  // ws layout (~70 MiB; <= proven-safe 74 MiB).
  char* p = (char*)d_ws;
  _Float16* region16 = (_Float16*)p;                   // 32 MiB
  _Float16* query16  = (_Float16*)(p + (32u << 20));   // 16 MiB
  _Float16* Qp       = (_Float16*)(p + (48u << 20));   // 16 MiB
  _Float16* M2       = (_Float16*)(p + (64u << 20));   // 2 MiB
  _Float16* Ws16     = (_Float16*)(p + (66u << 20));   // 4 KiB (Ws1|Ws2)
  float*    wqbr     = (float*)(p + (66u << 20) + 8192);    // 4 KiB
  _Float16* wqbr16   = (_Float16*)(p + (66u << 20) + 12288);// 2 KiB
  float*    cvec     = (float*)(p + (66u << 20) + 16384);   // 32 KiB
  float*    rdvec    = (float*)(p + (66u << 20) + 65536);   // 64 KiB
  float*    h1       = (float*)(p + (66u << 20) + 131072);  // 32 KiB
  float*    Ms       = (float*)(p + (67u << 20));      // 3 x 1 MiB stats
  float*    Ls       = Ms + 16 * BR;
  float*    Hs       = Ls + 16 * BR;

  // K1: M2 GEMM + all conversions + wqbr + rdvec + h1, one launch.
  prep_all<<<dim3(514 + BR / 4 + BD * TD / 4), 256, 0, stream>>>(
      Wr, Wq, Ws, br, region, query, M2, Ws16, wqbr, wqbr16,
      region16, rdvec, query16, h1);
  // K2: Qp = NT(query16, M2) + cvec epilogue (counted-vmcnt schedule).
  qp_gemm<<<dim3(512), 512, 0, stream>>>(query16, M2, Qp, wqbr16, cvec);
  // K3: fused S/H + split-softmax stats (3-slot counted-vmcnt schedule).
  gemm_fused<<<dim3(512), 512, 0, stream>>>(
      region16, Qp, query16, Ms, Ls, Hs, cvec, h1, Ws16,
      (long)RD * DD, (long)TD * DD);
  // K4: out = HS/L + region.Ws0 + bs.
  combine<<<dim3(BR / 256), 256, 0, stream>>>(Ms, Ls, Hs, rdvec, bs, out);
}